// Round 4
// baseline (1331.558 us; speedup 1.0000x reference)
//
#include <hip/hip_runtime.h>

// Masked scatter-mean, 3-kernel pipeline:
//   init_bcur     : bcur[b] = b*CAP  (fixed-capacity bucket cursors)
//   bin_fixed     : single edge pass; per-block LDS hist over 977 buckets,
//                   reserve ranges with one global atomic per (block,bucket),
//                   write packed (src<<10 | tgt&1023) into bucket windows
//   bucket_gather : one block per 1024-target bucket; gather feat rows
//                   edge-parallel (8 lanes/edge, unroll x2), accumulate into
//                   LDS sums (+counts), divide, stream out. No float atomics
//                   to global, no per-target CSR, no d_out memset.
// Fallback: R1 atomic path if ws too small / shapes out of range.

#define CCH 32
#define BSH 10           // bucket shift: 1024 targets per bucket
#define BKT 1024
#define CAP 16384        // slots per bucket (expected fill ~7345, 64 sigma)
#define BIN_TILE 16384
typedef unsigned int u32;

__global__ __launch_bounds__(256) void init_bcur_kernel(u32* __restrict__ bcur,
                                                        int NB) {
  int i = blockIdx.x * 256 + threadIdx.x;
  if (i < NB) bcur[i] = (u32)i * (u32)CAP;
}

__global__ __launch_bounds__(1024) void bin_fixed_kernel(
    const int* __restrict__ src_ids, const int* __restrict__ tgt_ids,
    const int* __restrict__ ntypes, u32* __restrict__ bcur,
    u32* __restrict__ pairs, int E, int NB) {
  __shared__ unsigned short s_b[BIN_TILE];  // bucket id per edge (0xFFFF = invalid)
  __shared__ u32 s_pw[BIN_TILE];            // packed (src<<10 | local_tgt)
  __shared__ u32 s_cnt[2048];
  __shared__ u32 s_base[2048];
  const long long base = (long long)blockIdx.x * BIN_TILE;

  for (int k = 0; k < BIN_TILE / 1024; ++k) {
    const int i = threadIdx.x + k * 1024;
    const long long e = base + i;
    unsigned short bb = 0xFFFFu;
    u32 pw = 0;
    if (e < E) {
      const long long eb = 3LL * e;
      if ((ntypes[eb] | ntypes[eb + 1] | ntypes[eb + 2]) >= 0) {
        const u32 t = (u32)tgt_ids[e];
        bb = (unsigned short)(t >> BSH);
        pw = ((u32)src_ids[e] << BSH) | (t & (BKT - 1u));
      }
    }
    s_b[i] = bb;
    s_pw[i] = pw;
  }
  for (int j = threadIdx.x; j < 2048; j += 1024) s_cnt[j] = 0;
  __syncthreads();

  for (int k = 0; k < BIN_TILE / 1024; ++k) {
    const int i = threadIdx.x + k * 1024;
    if (s_b[i] != 0xFFFFu) atomicAdd(&s_cnt[s_b[i]], 1u);
  }
  __syncthreads();

  for (int j = threadIdx.x; j < NB; j += 1024) {
    const u32 c = s_cnt[j];
    s_base[j] = c ? atomicAdd(&bcur[j], c) : 0u;
    s_cnt[j] = 0;
  }
  __syncthreads();

  for (int k = 0; k < BIN_TILE / 1024; ++k) {
    const int i = threadIdx.x + k * 1024;
    const unsigned short bb = s_b[i];
    if (bb != 0xFFFFu) {
      const u32 loc = atomicAdd(&s_cnt[bb], 1u);
      const u32 slot = s_base[bb] + loc;
      if (slot < ((u32)bb + 1u) * (u32)CAP) pairs[slot] = s_pw[i];  // overflow clamp
    }
  }
}

__global__ __launch_bounds__(1024, 1) void bucket_gather_kernel(
    const float* __restrict__ feat, const u32* __restrict__ pairs,
    const u32* __restrict__ bcur, float* __restrict__ out, int n_tgt) {
  __shared__ float s_sum[BKT * 33];  // 33-pad: spreads LDS-atomic banks, 132KB
  __shared__ u32 s_cnt[BKT];
  const int b = blockIdx.x;
  const u32 beg = (u32)b * (u32)CAP;
  u32 end = bcur[b];
  const u32 capend = beg + (u32)CAP;
  if (end > capend) end = capend;

  for (int j = threadIdx.x; j < BKT * 33; j += 1024) s_sum[j] = 0.f;
  s_cnt[threadIdx.x] = 0;  // blockDim == BKT == 1024
  __syncthreads();

  const int grp = threadIdx.x >> 3;   // 0..127: edge group
  const int lane = threadIdx.x & 7;   // 4 channels each
  const int l4 = lane * 4;

  for (u32 i0 = beg + grp; i0 < end; i0 += 256) {
    const u32 i1 = i0 + 128;
    const bool h1 = (i1 < end);
    const u32 pw0 = pairs[i0];
    const u32 pw1 = h1 ? pairs[i1] : 0u;
    // issue both gathers before any LDS work (2 outstanding / lane)
    const float4 v0 = *reinterpret_cast<const float4*>(
        feat + ((long long)(pw0 >> BSH)) * CCH + l4);
    float4 v1 = {0.f, 0.f, 0.f, 0.f};
    if (h1)
      v1 = *reinterpret_cast<const float4*>(
          feat + ((long long)(pw1 >> BSH)) * CCH + l4);

    const u32 lt0 = pw0 & (BKT - 1u);
    float* d0 = &s_sum[lt0 * 33 + l4];
    atomicAdd(d0 + 0, v0.x);
    atomicAdd(d0 + 1, v0.y);
    atomicAdd(d0 + 2, v0.z);
    atomicAdd(d0 + 3, v0.w);
    if (lane == 0) atomicAdd(&s_cnt[lt0], 1u);
    if (h1) {
      const u32 lt1 = pw1 & (BKT - 1u);
      float* d1 = &s_sum[lt1 * 33 + l4];
      atomicAdd(d1 + 0, v1.x);
      atomicAdd(d1 + 1, v1.y);
      atomicAdd(d1 + 2, v1.z);
      atomicAdd(d1 + 3, v1.w);
      if (lane == 0) atomicAdd(&s_cnt[lt1], 1u);
    }
  }
  __syncthreads();

  const long long t0 = (long long)b << BSH;
  for (int r = grp; r < BKT; r += 128) {
    const long long t = t0 + r;
    if (t < n_tgt) {
      const u32 c = s_cnt[r];
      const float inv = c ? 1.0f / (float)c : 0.0f;
      const int sbase = r * 33 + l4;
      float4 v;
      v.x = s_sum[sbase + 0] * inv;
      v.y = s_sum[sbase + 1] * inv;
      v.z = s_sum[sbase + 2] * inv;
      v.w = s_sum[sbase + 3] * inv;
      *reinterpret_cast<float4*>(out + t * CCH + l4) = v;
    }
  }
}

// ---------------- fallback: R1 atomic path ----------------

__global__ __launch_bounds__(256) void scatter_accum_kernel(
    const float* __restrict__ feat, const int* __restrict__ src_ids,
    const int* __restrict__ tgt_ids, const int* __restrict__ ntypes,
    float* __restrict__ sums, u32* __restrict__ counts,
    long long total_threads) {
  long long tid = (long long)blockIdx.x * blockDim.x + threadIdx.x;
  if (tid >= total_threads) return;
  const int e = (int)(tid >> 3);
  const int g = (int)(tid & 7);
  const long long eb = 3LL * e;
  if ((ntypes[eb] | ntypes[eb + 1] | ntypes[eb + 2]) < 0) return;
  const int s = src_ids[e];
  const int t = tgt_ids[e];
  const float4 v =
      *reinterpret_cast<const float4*>(feat + (long long)s * CCH + g * 4);
  float* dst = sums + (long long)t * CCH + g * 4;
  atomicAdd(dst + 0, v.x);
  atomicAdd(dst + 1, v.y);
  atomicAdd(dst + 2, v.z);
  atomicAdd(dst + 3, v.w);
  if (g == 0) atomicAdd(counts + t, 1u);
}

__global__ __launch_bounds__(256) void finalize_kernel(
    float* __restrict__ out, const u32* __restrict__ counts, int total_vec4) {
  int tid = blockIdx.x * blockDim.x + threadIdx.x;
  if (tid >= total_vec4) return;
  const int t = tid >> 3;
  const u32 cnt = counts[t];
  float4* p = reinterpret_cast<float4*>(out) + tid;
  float4 v = *p;
  const float inv = (cnt > 0u) ? (1.0f / (float)cnt) : 0.0f;
  v.x *= inv; v.y *= inv; v.z *= inv; v.w *= inv;
  *p = v;
}

// ---------------- launch ----------------

extern "C" void kernel_launch(void* const* d_in, const int* in_sizes, int n_in,
                              void* d_out, int out_size, void* d_ws,
                              size_t ws_size, hipStream_t stream) {
  const float* feat    = (const float*)d_in[0];
  const int*   src_ids = (const int*)d_in[1];
  const int*   tgt_ids = (const int*)d_in[2];
  const int*   ntypes  = (const int*)d_in[3];
  const int E     = in_sizes[1];
  const int n_src = in_sizes[0] / CCH;
  const int n_tgt = out_size / CCH;

  const int NB = (n_tgt + BKT - 1) >> BSH;

  // ws layout (u32): pairs[NB*CAP] | bcur[NB]
  const size_t need_fixed = ((size_t)NB * CAP + NB) * sizeof(u32);
  const bool shapes_ok =
      NB <= 2048 && n_src <= (1 << 22) &&
      (long long)E <= (long long)NB * CAP * 3 / 4;  // 64-sigma fill margin

  if (ws_size >= need_fixed && shapes_ok) {
    u32* pairs = (u32*)d_ws;
    u32* bcur  = pairs + (size_t)NB * CAP;

    init_bcur_kernel<<<(NB + 255) / 256, 256, 0, stream>>>(bcur, NB);
    const int bblocks = (E + BIN_TILE - 1) / BIN_TILE;
    bin_fixed_kernel<<<bblocks, 1024, 0, stream>>>(src_ids, tgt_ids, ntypes,
                                                   bcur, pairs, E, NB);
    bucket_gather_kernel<<<NB, 1024, 0, stream>>>(feat, pairs, bcur,
                                                  (float*)d_out, n_tgt);
  } else {
    float* sums   = (float*)d_out;
    u32*   counts = (u32*)d_ws;
    hipMemsetAsync(d_out, 0, (size_t)out_size * sizeof(float), stream);
    hipMemsetAsync(d_ws, 0, (size_t)n_tgt * sizeof(u32), stream);
    const long long total_threads = (long long)E * 8;
    const long long nblocks = (total_threads + 255) / 256;
    scatter_accum_kernel<<<(dim3)((unsigned int)nblocks), 256, 0, stream>>>(
        feat, src_ids, tgt_ids, ntypes, sums, counts, total_threads);
    const int total_vec4 = n_tgt * 8;
    finalize_kernel<<<(total_vec4 + 255) / 256, 256, 0, stream>>>(
        sums, counts, total_vec4);
  }
}

// Round 5
// 301.005 us; speedup vs baseline: 4.4237x; 4.4237x over previous
//
#include <hip/hip_runtime.h>

// Masked scatter-mean, 4-kernel pipeline (no float atomics anywhere):
//   init_bcur  : bcur[b] = b*CAP (fixed-capacity bucket window cursors)
//   bin_fixed  : ONE edge pass; LDS hist over buckets per block, reserve
//                ranges (1 global atomic per block*bucket), write packed
//                (src<<10 | tgt&1023) into per-bucket windows
//   csr_build  : one block per 1024-target bucket; stage window in LDS,
//                hist+scan local targets, scatter src ids back into the SAME
//                window (in-place CSR), write offsets[t] = cnt<<16 | local_beg
//   gather_reduce : 8 lanes/target, register accumulate, x4 unrolled feat
//                gather (4 independent 128B loads in flight), divide, store
// Fallback: R1 atomic path if ws too small / shapes out of range.

#define CCH 32
#define BSH 10            // 1024 targets per bucket
#define BKT 1024
#define CAP 14336         // slots per bucket window (mean fill ~7345)
#define BIN_TILE 8192
typedef unsigned int u32;

__global__ __launch_bounds__(256) void init_bcur_kernel(u32* __restrict__ bcur,
                                                        int NB) {
  int i = blockIdx.x * 256 + threadIdx.x;
  if (i < NB) bcur[i] = (u32)i * (u32)CAP;
}

__global__ __launch_bounds__(1024) void bin_fixed_kernel(
    const int* __restrict__ src_ids, const int* __restrict__ tgt_ids,
    const int* __restrict__ ntypes, u32* __restrict__ bcur,
    u32* __restrict__ pairs, int E, int NB) {
  __shared__ unsigned short s_b[BIN_TILE];  // bucket id (0xFFFF = invalid)
  __shared__ u32 s_pw[BIN_TILE];            // packed (src<<10 | local_tgt)
  __shared__ u32 s_cnt[2048];
  __shared__ u32 s_base[2048];
  const long long base = (long long)blockIdx.x * BIN_TILE;

  for (int k = 0; k < BIN_TILE / 1024; ++k) {
    const int i = threadIdx.x + k * 1024;
    const long long e = base + i;
    unsigned short bb = 0xFFFFu;
    u32 pw = 0;
    if (e < E) {
      const long long eb = 3LL * e;
      if ((ntypes[eb] | ntypes[eb + 1] | ntypes[eb + 2]) >= 0) {
        const u32 t = (u32)tgt_ids[e];
        bb = (unsigned short)(t >> BSH);
        pw = ((u32)src_ids[e] << BSH) | (t & (BKT - 1u));
      }
    }
    s_b[i] = bb;
    s_pw[i] = pw;
  }
  for (int j = threadIdx.x; j < 2048; j += 1024) s_cnt[j] = 0;
  __syncthreads();

  for (int k = 0; k < BIN_TILE / 1024; ++k) {
    const int i = threadIdx.x + k * 1024;
    if (s_b[i] != 0xFFFFu) atomicAdd(&s_cnt[s_b[i]], 1u);
  }
  __syncthreads();

  for (int j = threadIdx.x; j < NB; j += 1024) {
    const u32 c = s_cnt[j];
    s_base[j] = c ? atomicAdd(&bcur[j], c) : 0u;
    s_cnt[j] = 0;
  }
  __syncthreads();

  for (int k = 0; k < BIN_TILE / 1024; ++k) {
    const int i = threadIdx.x + k * 1024;
    const unsigned short bb = s_b[i];
    if (bb != 0xFFFFu) {
      const u32 loc = atomicAdd(&s_cnt[bb], 1u);
      const u32 slot = s_base[bb] + loc;
      if (slot < ((u32)bb + 1u) * (u32)CAP) pairs[slot] = s_pw[i];  // clamp
    }
  }
}

__global__ __launch_bounds__(1024) void csr_build_kernel(
    u32* __restrict__ pairs, const u32* __restrict__ bcur,
    u32* __restrict__ offsets, int n_tgt) {
  __shared__ u32 s_pw[CAP];   // 56 KB staged window
  __shared__ u32 s_cnt[BKT];  // hist, then scatter cursors
  __shared__ u32 s_off[BKT];  // inclusive scan
  const int b = blockIdx.x;
  const u32 wbeg = (u32)b * (u32)CAP;
  u32 fill = bcur[b] - wbeg;
  if (fill > (u32)CAP) fill = (u32)CAP;

  for (u32 i = threadIdx.x; i < fill; i += 1024) s_pw[i] = pairs[wbeg + i];
  s_cnt[threadIdx.x] = 0;  // blockDim == BKT
  __syncthreads();
  for (u32 i = threadIdx.x; i < fill; i += 1024)
    atomicAdd(&s_cnt[s_pw[i] & (BKT - 1u)], 1u);
  __syncthreads();

  const u32 v = s_cnt[threadIdx.x];
  s_off[threadIdx.x] = v;
  __syncthreads();
  for (int d = 1; d < BKT; d <<= 1) {
    const u32 add = (threadIdx.x >= (unsigned)d) ? s_off[threadIdx.x - d] : 0u;
    __syncthreads();
    s_off[threadIdx.x] += add;
    __syncthreads();
  }
  const u32 excl = s_off[threadIdx.x] - v;

  const int t0 = b << BSH;
  if (t0 + (int)threadIdx.x < n_tgt)
    offsets[t0 + threadIdx.x] = (v << 16) | excl;  // cnt<<16 | local_beg

  s_cnt[threadIdx.x] = excl;  // scatter cursors
  __syncthreads();
  for (u32 i = threadIdx.x; i < fill; i += 1024) {
    const u32 pw = s_pw[i];
    const u32 loc = atomicAdd(&s_cnt[pw & (BKT - 1u)], 1u);
    pairs[wbeg + loc] = pw >> BSH;  // in-place: src id, sorted by local tgt
  }
}

__global__ __launch_bounds__(256) void gather_reduce_kernel(
    const float* __restrict__ feat, const u32* __restrict__ csr,
    const u32* __restrict__ offsets, float* __restrict__ out, int n_tgt) {
  const int tid = blockIdx.x * 256 + threadIdx.x;
  const int t = tid >> 3;
  const int g = tid & 7;
  if (t >= n_tgt) return;
  const u32 off = offsets[t];
  const u32 n = off >> 16;
  u32 i = ((u32)(t >> BSH)) * (u32)CAP + (off & 0xFFFFu);
  const u32 end = i + n;
  const int l4 = g * 4;

  float4 a0 = {0.f, 0.f, 0.f, 0.f}, a1 = {0.f, 0.f, 0.f, 0.f};
  float4 a2 = {0.f, 0.f, 0.f, 0.f}, a3 = {0.f, 0.f, 0.f, 0.f};
  for (; i + 4 <= end; i += 4) {
    const u32 s0 = csr[i + 0], s1 = csr[i + 1], s2 = csr[i + 2],
              s3 = csr[i + 3];
    const float4 v0 =
        *reinterpret_cast<const float4*>(feat + (long long)s0 * CCH + l4);
    const float4 v1 =
        *reinterpret_cast<const float4*>(feat + (long long)s1 * CCH + l4);
    const float4 v2 =
        *reinterpret_cast<const float4*>(feat + (long long)s2 * CCH + l4);
    const float4 v3 =
        *reinterpret_cast<const float4*>(feat + (long long)s3 * CCH + l4);
    a0.x += v0.x; a0.y += v0.y; a0.z += v0.z; a0.w += v0.w;
    a1.x += v1.x; a1.y += v1.y; a1.z += v1.z; a1.w += v1.w;
    a2.x += v2.x; a2.y += v2.y; a2.z += v2.z; a2.w += v2.w;
    a3.x += v3.x; a3.y += v3.y; a3.z += v3.z; a3.w += v3.w;
  }
  for (; i < end; ++i) {
    const u32 s0 = csr[i];
    const float4 v0 =
        *reinterpret_cast<const float4*>(feat + (long long)s0 * CCH + l4);
    a0.x += v0.x; a0.y += v0.y; a0.z += v0.z; a0.w += v0.w;
  }
  const float inv = n ? 1.0f / (float)n : 0.0f;
  float4 r;
  r.x = (a0.x + a1.x + a2.x + a3.x) * inv;
  r.y = (a0.y + a1.y + a2.y + a3.y) * inv;
  r.z = (a0.z + a1.z + a2.z + a3.z) * inv;
  r.w = (a0.w + a1.w + a2.w + a3.w) * inv;
  *reinterpret_cast<float4*>(out + (long long)t * CCH + l4) = r;
}

// ---------------- fallback: R1 atomic path ----------------

__global__ __launch_bounds__(256) void scatter_accum_kernel(
    const float* __restrict__ feat, const int* __restrict__ src_ids,
    const int* __restrict__ tgt_ids, const int* __restrict__ ntypes,
    float* __restrict__ sums, u32* __restrict__ counts,
    long long total_threads) {
  long long tid = (long long)blockIdx.x * blockDim.x + threadIdx.x;
  if (tid >= total_threads) return;
  const int e = (int)(tid >> 3);
  const int g = (int)(tid & 7);
  const long long eb = 3LL * e;
  if ((ntypes[eb] | ntypes[eb + 1] | ntypes[eb + 2]) < 0) return;
  const int s = src_ids[e];
  const int t = tgt_ids[e];
  const float4 v =
      *reinterpret_cast<const float4*>(feat + (long long)s * CCH + g * 4);
  float* dst = sums + (long long)t * CCH + g * 4;
  atomicAdd(dst + 0, v.x);
  atomicAdd(dst + 1, v.y);
  atomicAdd(dst + 2, v.z);
  atomicAdd(dst + 3, v.w);
  if (g == 0) atomicAdd(counts + t, 1u);
}

__global__ __launch_bounds__(256) void finalize_kernel(
    float* __restrict__ out, const u32* __restrict__ counts, int total_vec4) {
  int tid = blockIdx.x * blockDim.x + threadIdx.x;
  if (tid >= total_vec4) return;
  const int t = tid >> 3;
  const u32 cnt = counts[t];
  float4* p = reinterpret_cast<float4*>(out) + tid;
  float4 v = *p;
  const float inv = (cnt > 0u) ? (1.0f / (float)cnt) : 0.0f;
  v.x *= inv; v.y *= inv; v.z *= inv; v.w *= inv;
  *p = v;
}

// ---------------- launch ----------------

extern "C" void kernel_launch(void* const* d_in, const int* in_sizes, int n_in,
                              void* d_out, int out_size, void* d_ws,
                              size_t ws_size, hipStream_t stream) {
  const float* feat    = (const float*)d_in[0];
  const int*   src_ids = (const int*)d_in[1];
  const int*   tgt_ids = (const int*)d_in[2];
  const int*   ntypes  = (const int*)d_in[3];
  const int E     = in_sizes[1];
  const int n_src = in_sizes[0] / CCH;
  const int n_tgt = out_size / CCH;

  const int NB = (n_tgt + BKT - 1) >> BSH;

  // ws layout (u32): pairs/csr windows [NB*CAP] | bcur[NB] | offsets[n_tgt]
  const size_t need =
      ((size_t)NB * CAP + NB + (size_t)n_tgt) * sizeof(u32);
  const bool shapes_ok =
      NB <= 2048 && n_src <= (1 << 22) &&
      (long long)E <= (long long)NB * CAP * 3 / 4;  // fill margin

  if (ws_size >= need && shapes_ok) {
    u32* pairs   = (u32*)d_ws;
    u32* bcur    = pairs + (size_t)NB * CAP;
    u32* offsets = bcur + NB;

    init_bcur_kernel<<<(NB + 255) / 256, 256, 0, stream>>>(bcur, NB);
    const int bblocks = (E + BIN_TILE - 1) / BIN_TILE;
    bin_fixed_kernel<<<bblocks, 1024, 0, stream>>>(src_ids, tgt_ids, ntypes,
                                                   bcur, pairs, E, NB);
    csr_build_kernel<<<NB, 1024, 0, stream>>>(pairs, bcur, offsets, n_tgt);
    const long long gthreads = (long long)n_tgt * 8;
    const int gblocks = (int)((gthreads + 255) / 256);
    gather_reduce_kernel<<<gblocks, 256, 0, stream>>>(feat, pairs, offsets,
                                                      (float*)d_out, n_tgt);
  } else {
    float* sums   = (float*)d_out;
    u32*   counts = (u32*)d_ws;
    hipMemsetAsync(d_out, 0, (size_t)out_size * sizeof(float), stream);
    hipMemsetAsync(d_ws, 0, (size_t)n_tgt * sizeof(u32), stream);
    const long long total_threads = (long long)E * 8;
    const long long nblocks = (total_threads + 255) / 256;
    scatter_accum_kernel<<<(dim3)((unsigned int)nblocks), 256, 0, stream>>>(
        feat, src_ids, tgt_ids, ntypes, sums, counts, total_threads);
    const int total_vec4 = n_tgt * 8;
    finalize_kernel<<<(total_vec4 + 255) / 256, 256, 0, stream>>>(
        sums, counts, total_vec4);
  }
}

// Round 6
// 295.507 us; speedup vs baseline: 4.5060x; 1.0186x over previous
//
#include <hip/hip_runtime.h>

// Masked scatter-mean, 4-kernel pipeline (no float atomics anywhere):
//   init_bcur  : bcur[b] = b*CAP (fixed-capacity bucket window cursors)
//   bin_fixed  : ONE edge pass; LDS hist over buckets per block, reserve
//                ranges (1 global atomic per block*bucket), write packed
//                (src<<10 | tgt&1023) into per-bucket windows
//   csr_build  : one block per 1024-target bucket; stage window in LDS,
//                hist+scan local targets, scatter src ids back into the SAME
//                window (in-place CSR), write offsets[t] = cnt<<16 | local_beg
//   gather_reduce : 8 lanes/target; PREDICATED 8-deep gather pipeline
//                (index-clamped loads + masked accumulate -> 8 outstanding
//                128B feat loads regardless of segment length), divide, store
// Fallback: R1 atomic path if ws too small / shapes out of range.

#define CCH 32
#define BSH 10            // 1024 targets per bucket
#define BKT 1024
#define CAP 14336         // slots per bucket window (mean fill ~7345)
#define BIN_TILE 8192
typedef unsigned int u32;

__global__ __launch_bounds__(256) void init_bcur_kernel(u32* __restrict__ bcur,
                                                        int NB) {
  int i = blockIdx.x * 256 + threadIdx.x;
  if (i < NB) bcur[i] = (u32)i * (u32)CAP;
}

__global__ __launch_bounds__(1024) void bin_fixed_kernel(
    const int* __restrict__ src_ids, const int* __restrict__ tgt_ids,
    const int* __restrict__ ntypes, u32* __restrict__ bcur,
    u32* __restrict__ pairs, int E, int NB) {
  __shared__ unsigned short s_b[BIN_TILE];  // bucket id (0xFFFF = invalid)
  __shared__ u32 s_pw[BIN_TILE];            // packed (src<<10 | local_tgt)
  __shared__ u32 s_cnt[2048];
  __shared__ u32 s_base[2048];
  const long long base = (long long)blockIdx.x * BIN_TILE;

  for (int k = 0; k < BIN_TILE / 1024; ++k) {
    const int i = threadIdx.x + k * 1024;
    const long long e = base + i;
    unsigned short bb = 0xFFFFu;
    u32 pw = 0;
    if (e < E) {
      const long long eb = 3LL * e;
      if ((ntypes[eb] | ntypes[eb + 1] | ntypes[eb + 2]) >= 0) {
        const u32 t = (u32)tgt_ids[e];
        bb = (unsigned short)(t >> BSH);
        pw = ((u32)src_ids[e] << BSH) | (t & (BKT - 1u));
      }
    }
    s_b[i] = bb;
    s_pw[i] = pw;
  }
  for (int j = threadIdx.x; j < 2048; j += 1024) s_cnt[j] = 0;
  __syncthreads();

  for (int k = 0; k < BIN_TILE / 1024; ++k) {
    const int i = threadIdx.x + k * 1024;
    if (s_b[i] != 0xFFFFu) atomicAdd(&s_cnt[s_b[i]], 1u);
  }
  __syncthreads();

  for (int j = threadIdx.x; j < NB; j += 1024) {
    const u32 c = s_cnt[j];
    s_base[j] = c ? atomicAdd(&bcur[j], c) : 0u;
    s_cnt[j] = 0;
  }
  __syncthreads();

  for (int k = 0; k < BIN_TILE / 1024; ++k) {
    const int i = threadIdx.x + k * 1024;
    const unsigned short bb = s_b[i];
    if (bb != 0xFFFFu) {
      const u32 loc = atomicAdd(&s_cnt[bb], 1u);
      const u32 slot = s_base[bb] + loc;
      if (slot < ((u32)bb + 1u) * (u32)CAP) pairs[slot] = s_pw[i];  // clamp
    }
  }
}

__global__ __launch_bounds__(1024) void csr_build_kernel(
    u32* __restrict__ pairs, const u32* __restrict__ bcur,
    u32* __restrict__ offsets, int n_tgt) {
  __shared__ u32 s_pw[CAP];   // 56 KB staged window
  __shared__ u32 s_cnt[BKT];  // hist, then scatter cursors
  __shared__ u32 s_off[BKT];  // inclusive scan
  const int b = blockIdx.x;
  const u32 wbeg = (u32)b * (u32)CAP;
  u32 fill = bcur[b] - wbeg;
  if (fill > (u32)CAP) fill = (u32)CAP;

  for (u32 i = threadIdx.x; i < fill; i += 1024) s_pw[i] = pairs[wbeg + i];
  s_cnt[threadIdx.x] = 0;  // blockDim == BKT
  __syncthreads();
  for (u32 i = threadIdx.x; i < fill; i += 1024)
    atomicAdd(&s_cnt[s_pw[i] & (BKT - 1u)], 1u);
  __syncthreads();

  const u32 v = s_cnt[threadIdx.x];
  s_off[threadIdx.x] = v;
  __syncthreads();
  for (int d = 1; d < BKT; d <<= 1) {
    const u32 add = (threadIdx.x >= (unsigned)d) ? s_off[threadIdx.x - d] : 0u;
    __syncthreads();
    s_off[threadIdx.x] += add;
    __syncthreads();
  }
  const u32 excl = s_off[threadIdx.x] - v;

  const int t0 = b << BSH;
  if (t0 + (int)threadIdx.x < n_tgt)
    offsets[t0 + threadIdx.x] = (v << 16) | excl;  // cnt<<16 | local_beg

  s_cnt[threadIdx.x] = excl;  // scatter cursors
  __syncthreads();
  for (u32 i = threadIdx.x; i < fill; i += 1024) {
    const u32 pw = s_pw[i];
    const u32 loc = atomicAdd(&s_cnt[pw & (BKT - 1u)], 1u);
    pairs[wbeg + loc] = pw >> BSH;  // in-place: src id, sorted by local tgt
  }
}

__global__ __launch_bounds__(256) void gather_reduce_kernel(
    const float* __restrict__ feat, const u32* __restrict__ csr,
    const u32* __restrict__ offsets, float* __restrict__ out, int n_tgt) {
  const int tid = blockIdx.x * 256 + threadIdx.x;
  const int t = tid >> 3;
  const int g = tid & 7;
  if (t >= n_tgt) return;
  const u32 off = offsets[t];
  const u32 n = off >> 16;
  const u32 base = ((u32)(t >> BSH)) * (u32)CAP + (off & 0xFFFFu);
  const int l4 = g * 4;

  float4 acc = {0.f, 0.f, 0.f, 0.f};
  for (u32 c = 0; c < n; c += 8) {
    const u32 m = n - c;  // >= 1
    u32 idx[8];
#pragma unroll
    for (int k = 0; k < 8; ++k)
      idx[k] = csr[base + c + ((u32)k < m ? (u32)k : 0u)];
    float4 v[8];
#pragma unroll
    for (int k = 0; k < 8; ++k)
      v[k] = *reinterpret_cast<const float4*>(feat +
                                              (long long)idx[k] * CCH + l4);
#pragma unroll
    for (int k = 0; k < 8; ++k) {
      const float w = ((u32)k < m) ? 1.0f : 0.0f;
      acc.x += v[k].x * w;
      acc.y += v[k].y * w;
      acc.z += v[k].z * w;
      acc.w += v[k].w * w;
    }
  }
  const float inv = n ? 1.0f / (float)n : 0.0f;
  float4 r;
  r.x = acc.x * inv;
  r.y = acc.y * inv;
  r.z = acc.z * inv;
  r.w = acc.w * inv;
  *reinterpret_cast<float4*>(out + (long long)t * CCH + l4) = r;
}

// ---------------- fallback: R1 atomic path ----------------

__global__ __launch_bounds__(256) void scatter_accum_kernel(
    const float* __restrict__ feat, const int* __restrict__ src_ids,
    const int* __restrict__ tgt_ids, const int* __restrict__ ntypes,
    float* __restrict__ sums, u32* __restrict__ counts,
    long long total_threads) {
  long long tid = (long long)blockIdx.x * blockDim.x + threadIdx.x;
  if (tid >= total_threads) return;
  const int e = (int)(tid >> 3);
  const int g = (int)(tid & 7);
  const long long eb = 3LL * e;
  if ((ntypes[eb] | ntypes[eb + 1] | ntypes[eb + 2]) < 0) return;
  const int s = src_ids[e];
  const int t = tgt_ids[e];
  const float4 v =
      *reinterpret_cast<const float4*>(feat + (long long)s * CCH + g * 4);
  float* dst = sums + (long long)t * CCH + g * 4;
  atomicAdd(dst + 0, v.x);
  atomicAdd(dst + 1, v.y);
  atomicAdd(dst + 2, v.z);
  atomicAdd(dst + 3, v.w);
  if (g == 0) atomicAdd(counts + t, 1u);
}

__global__ __launch_bounds__(256) void finalize_kernel(
    float* __restrict__ out, const u32* __restrict__ counts, int total_vec4) {
  int tid = blockIdx.x * blockDim.x + threadIdx.x;
  if (tid >= total_vec4) return;
  const int t = tid >> 3;
  const u32 cnt = counts[t];
  float4* p = reinterpret_cast<float4*>(out) + tid;
  float4 v = *p;
  const float inv = (cnt > 0u) ? (1.0f / (float)cnt) : 0.0f;
  v.x *= inv; v.y *= inv; v.z *= inv; v.w *= inv;
  *p = v;
}

// ---------------- launch ----------------

extern "C" void kernel_launch(void* const* d_in, const int* in_sizes, int n_in,
                              void* d_out, int out_size, void* d_ws,
                              size_t ws_size, hipStream_t stream) {
  const float* feat    = (const float*)d_in[0];
  const int*   src_ids = (const int*)d_in[1];
  const int*   tgt_ids = (const int*)d_in[2];
  const int*   ntypes  = (const int*)d_in[3];
  const int E     = in_sizes[1];
  const int n_src = in_sizes[0] / CCH;
  const int n_tgt = out_size / CCH;

  const int NB = (n_tgt + BKT - 1) >> BSH;

  // ws layout (u32): pairs/csr windows [NB*CAP] | bcur[NB] | offsets[n_tgt]
  const size_t need =
      ((size_t)NB * CAP + NB + (size_t)n_tgt) * sizeof(u32);
  const bool shapes_ok =
      NB <= 2048 && n_src <= (1 << 22) &&
      (long long)E <= (long long)NB * CAP * 3 / 4;  // fill margin

  if (ws_size >= need && shapes_ok) {
    u32* pairs   = (u32*)d_ws;
    u32* bcur    = pairs + (size_t)NB * CAP;
    u32* offsets = bcur + NB;

    init_bcur_kernel<<<(NB + 255) / 256, 256, 0, stream>>>(bcur, NB);
    const int bblocks = (E + BIN_TILE - 1) / BIN_TILE;
    bin_fixed_kernel<<<bblocks, 1024, 0, stream>>>(src_ids, tgt_ids, ntypes,
                                                   bcur, pairs, E, NB);
    csr_build_kernel<<<NB, 1024, 0, stream>>>(pairs, bcur, offsets, n_tgt);
    const long long gthreads = (long long)n_tgt * 8;
    const int gblocks = (int)((gthreads + 255) / 256);
    gather_reduce_kernel<<<gblocks, 256, 0, stream>>>(feat, pairs, offsets,
                                                      (float*)d_out, n_tgt);
  } else {
    float* sums   = (float*)d_out;
    u32*   counts = (u32*)d_ws;
    hipMemsetAsync(d_out, 0, (size_t)out_size * sizeof(float), stream);
    hipMemsetAsync(d_ws, 0, (size_t)n_tgt * sizeof(u32), stream);
    const long long total_threads = (long long)E * 8;
    const long long nblocks = (total_threads + 255) / 256;
    scatter_accum_kernel<<<(dim3)((unsigned int)nblocks), 256, 0, stream>>>(
        feat, src_ids, tgt_ids, ntypes, sums, counts, total_threads);
    const int total_vec4 = n_tgt * 8;
    finalize_kernel<<<(total_vec4 + 255) / 256, 256, 0, stream>>>(
        sums, counts, total_vec4);
  }
}